// Round 2
// baseline (1399.092 us; speedup 1.0000x reference)
//
#include <hip/hip_runtime.h>
#include <math.h>

// Problem constants (B=4, C=64, H=W=192, K=3)
constexpr int Hh  = 192;
constexpr int Ww  = 192;
constexpr int HWp = Hh * Ww;      // 36864
constexpr int Cc  = 64;
constexpr int Bb  = 4;
constexpr int KK  = 9;
constexpr int OFFC = 18;          // 2*K*K
constexpr int PX  = 16;           // pixels per block in deform kernel

// ---------------- Kernel 1: 3x3 offset-generating conv ----------------
__global__ __launch_bounds__(256)
void k_offset_conv(const float* __restrict__ x, const float* __restrict__ Woff,
                   const float* __restrict__ boff, float* __restrict__ offset) {
    int idx = blockIdx.x * 256 + threadIdx.x;           // over B*18*H*W
    int w  = idx % Ww;
    int h  = (idx / Ww) % Hh;
    int oc = (idx / HWp) % OFFC;
    int b  = idx / (HWp * OFFC);
    float acc = boff[oc];
    const float* xb = x + (size_t)b * Cc * HWp;
    const float* wr = Woff + oc * Cc * 9;
    for (int ic = 0; ic < Cc; ++ic) {
        const float* xp = xb + ic * HWp;
        const float* wp = wr + ic * 9;
        #pragma unroll
        for (int t = 0; t < 9; ++t) {
            int yy = h + t / 3 - 1;
            int xx = w + t % 3 - 1;
            if (yy >= 0 && yy < Hh && xx >= 0 && xx < Ww)
                acc = fmaf(wp[t], xp[yy * Ww + xx], acc);
        }
    }
    offset[idx] = acc;
}

// ---------------- Kernel 2: transpose weights for coalesced reads ----------------
__global__ __launch_bounds__(256)
void k_transpose(const float* __restrict__ Wd, const float* __restrict__ Wc,
                 float* __restrict__ WdT, float* __restrict__ WcT) {
    int i = blockIdx.x * 256 + threadIdx.x;
    if (i < Cc * Cc * KK) {                 // W_def [o][c*9+kk] -> [c*9+kk][o]
        int o = i / (Cc * KK), ck = i % (Cc * KK);
        WdT[ck * Cc + o] = Wd[i];
    }
    if (i < Cc * Cc) {                      // W_cat [o][c] -> [c][o]
        int o = i / Cc, c = i % Cc;
        WcT[c * Cc + o] = Wc[i];
    }
}

// ---------------- Kernel 3: deformable conv + 1x1 conv fused ----------------
__global__ __launch_bounds__(256)
void k_deform(const float* __restrict__ x, const float* __restrict__ offset,
              const float* __restrict__ WdT, const float* __restrict__ bdef,
              const float* __restrict__ WcT, const float* __restrict__ bcat,
              float* __restrict__ y) {
    __shared__ int   s_i00[KK * PX], s_i01[KK * PX], s_i10[KK * PX], s_i11[KK * PX];
    __shared__ float s_w00[KK * PX], s_w01[KK * PX], s_w10[KK * PX], s_w11[KK * PX];
    __shared__ float s_samp[Cc * KK * PX];   // [(c*9+kk)*PX + pxi]  ~36.9 KB
    __shared__ float s_y1[PX * Cc];          // [pxi*64 + c]

    const int t   = threadIdx.x;
    const int bpx = blockIdx.x % (HWp / PX);
    const int b   = blockIdx.x / (HWp / PX);
    const int px0 = bpx * PX;

    // Phase 0: bilinear params for 9 taps x 16 pixels
    if (t < KK * PX) {
        int pxi = t % PX, kk = t / PX;
        int px = px0 + pxi;
        int h = px / Ww, w = px % Ww;
        const float offy = offset[((size_t)b * OFFC + kk * 2    ) * HWp + px];
        const float offx = offset[((size_t)b * OFFC + kk * 2 + 1) * HWp + px];
        float py  = offy + (float)(h - 1 + kk / 3);
        float pxf = offx + (float)(w - 1 + kk % 3);
        float fy0 = floorf(py), fx0 = floorf(pxf);
        float wy = py - fy0, wx = pxf - fx0;
        int iy0 = (int)fy0, ix0 = (int)fx0;
        int iy1 = iy0 + 1,  ix1 = ix0 + 1;
        float v00 = (iy0 >= 0 && iy0 < Hh && ix0 >= 0 && ix0 < Ww) ? 1.f : 0.f;
        float v01 = (iy0 >= 0 && iy0 < Hh && ix1 >= 0 && ix1 < Ww) ? 1.f : 0.f;
        float v10 = (iy1 >= 0 && iy1 < Hh && ix0 >= 0 && ix0 < Ww) ? 1.f : 0.f;
        float v11 = (iy1 >= 0 && iy1 < Hh && ix1 >= 0 && ix1 < Ww) ? 1.f : 0.f;
        int cy0 = min(max(iy0, 0), Hh - 1), cy1 = min(max(iy1, 0), Hh - 1);
        int cx0 = min(max(ix0, 0), Ww - 1), cx1 = min(max(ix1, 0), Ww - 1);
        s_i00[t] = cy0 * Ww + cx0;  s_i01[t] = cy0 * Ww + cx1;
        s_i10[t] = cy1 * Ww + cx0;  s_i11[t] = cy1 * Ww + cx1;
        s_w00[t] = (1.f - wy) * (1.f - wx) * v00;
        s_w01[t] = (1.f - wy) * wx * v01;
        s_w10[t] = wy * (1.f - wx) * v10;
        s_w11[t] = wy * wx * v11;
    }
    __syncthreads();

    // Phase 1: bilinear sampling into LDS (64 ch x 9 taps x 16 px)
    const float* xb = x + (size_t)b * Cc * HWp;
    for (int i = t; i < Cc * KK * PX; i += 256) {
        int pxi = i & (PX - 1);
        int ckk = i >> 4;            // PX == 16
        int kk = ckk % KK;
        int c  = ckk / KK;
        int j  = kk * PX + pxi;
        const float* xp = xb + c * HWp;
        float v = s_w00[j] * xp[s_i00[j]] + s_w01[j] * xp[s_i01[j]]
                + s_w10[j] * xp[s_i10[j]] + s_w11[j] * xp[s_i11[j]];
        s_samp[i] = v;
    }
    __syncthreads();

    // Phase 2: deform contraction  y1[px][o] = sum_ck samp[ck][px] * WdT[ck][o]
    const int o  = t & 63;
    const int pg = t >> 6;           // 0..3, each handles 4 pixels
    float bv = bdef[o];
    float a0 = bv, a1 = bv, a2 = bv, a3 = bv;
    #pragma unroll 4
    for (int ck = 0; ck < Cc * KK; ++ck) {
        float wv = WdT[ck * Cc + o];
        float4 sv = *reinterpret_cast<const float4*>(&s_samp[ck * PX + pg * 4]);
        a0 = fmaf(wv, sv.x, a0);
        a1 = fmaf(wv, sv.y, a1);
        a2 = fmaf(wv, sv.z, a2);
        a3 = fmaf(wv, sv.w, a3);
    }
    s_y1[(pg * 4 + 0) * Cc + o] = a0;
    s_y1[(pg * 4 + 1) * Cc + o] = a1;
    s_y1[(pg * 4 + 2) * Cc + o] = a2;
    s_y1[(pg * 4 + 3) * Cc + o] = a3;
    __syncthreads();

    // Phase 3: 1x1 conv  y[px][o] = sum_c y1[px][c] * WcT[c][o] + bcat[o]
    float z0 = 0.f, z1 = 0.f, z2 = 0.f, z3 = 0.f;
    #pragma unroll 8
    for (int c = 0; c < Cc; ++c) {
        float wv = WcT[c * Cc + o];
        z0 = fmaf(wv, s_y1[(pg * 4 + 0) * Cc + c], z0);
        z1 = fmaf(wv, s_y1[(pg * 4 + 1) * Cc + c], z1);
        z2 = fmaf(wv, s_y1[(pg * 4 + 2) * Cc + c], z2);
        z3 = fmaf(wv, s_y1[(pg * 4 + 3) * Cc + c], z3);
    }
    float bc = bcat[o];
    size_t base = ((size_t)(b * Cc + o)) * HWp + px0 + pg * 4;
    y[base + 0] = z0 + bc;
    y[base + 1] = z1 + bc;
    y[base + 2] = z2 + bc;
    y[base + 3] = z3 + bc;
}

// ---------------- Kernel 4: per-channel batch stats ----------------
__global__ __launch_bounds__(256)
void k_stats(const float* __restrict__ y, float* __restrict__ stats) {
    int c = blockIdx.x;
    double s1 = 0.0, s2 = 0.0;
    for (int p = threadIdx.x; p < Bb * HWp; p += 256) {
        int b = p / HWp, sp = p % HWp;
        float v = y[((size_t)b * Cc + c) * HWp + sp];
        s1 += (double)v;
        s2 += (double)v * (double)v;
    }
    for (int d = 32; d >= 1; d >>= 1) {
        s1 += __shfl_down(s1, d);
        s2 += __shfl_down(s2, d);
    }
    __shared__ double r1[4], r2[4];
    int wave = threadIdx.x >> 6, lane = threadIdx.x & 63;
    if (lane == 0) { r1[wave] = s1; r2[wave] = s2; }
    __syncthreads();
    if (threadIdx.x == 0) {
        double t1 = r1[0] + r1[1] + r1[2] + r1[3];
        double t2 = r2[0] + r2[1] + r2[2] + r2[3];
        double n = (double)(Bb * HWp);
        double mean = t1 / n;
        double var  = t2 / n - mean * mean;
        stats[c]      = (float)mean;
        stats[Cc + c] = (float)(1.0 / sqrt(var + 1e-5));
    }
}

// ---------------- Kernel 5: BN apply + ReLU + residual ----------------
__global__ __launch_bounds__(256)
void k_apply(const float* __restrict__ y, const float* __restrict__ x,
             const float* __restrict__ stats, const float* __restrict__ gamma,
             const float* __restrict__ beta, float* __restrict__ out) {
    int idx = blockIdx.x * 256 + threadIdx.x;           // over B*C*H*W
    int c = (idx / HWp) % Cc;
    float mean = stats[c], inv = stats[Cc + c];
    float v = (y[idx] - mean) * inv;
    v = gamma[c] * v + beta[c];
    v = fmaxf(v, 0.f);
    out[idx] = v + x[idx];
}

extern "C" void kernel_launch(void* const* d_in, const int* in_sizes, int n_in,
                              void* d_out, int out_size, void* d_ws, size_t ws_size,
                              hipStream_t stream) {
    const float* x     = (const float*)d_in[0];
    const float* Woff  = (const float*)d_in[1];
    const float* boff  = (const float*)d_in[2];
    const float* Wdef  = (const float*)d_in[3];
    const float* bdef  = (const float*)d_in[4];
    const float* Wcat  = (const float*)d_in[5];
    const float* bcat  = (const float*)d_in[6];
    const float* gamma = (const float*)d_in[7];
    const float* beta  = (const float*)d_in[8];
    float* out = (float*)d_out;

    float* ws     = (float*)d_ws;
    float* offset = ws;                              // B*18*HW   = 2,654,208
    float* ybuf   = offset + (size_t)Bb * OFFC * HWp; // B*64*HW  = 9,437,184
    float* WdT    = ybuf + (size_t)Bb * Cc * HWp;    // 36,864
    float* WcT    = WdT + Cc * Cc * KK;              // 4,096
    float* stats  = WcT + Cc * Cc;                   // 128

    k_offset_conv<<<dim3(Bb * OFFC * HWp / 256), dim3(256), 0, stream>>>(x, Woff, boff, offset);
    k_transpose<<<dim3((Cc * Cc * KK + 255) / 256), dim3(256), 0, stream>>>(Wdef, Wcat, WdT, WcT);
    k_deform<<<dim3(Bb * (HWp / PX)), dim3(256), 0, stream>>>(x, offset, WdT, bdef, WcT, bcat, ybuf);
    k_stats<<<dim3(Cc), dim3(256), 0, stream>>>(ybuf, stats);
    k_apply<<<dim3(Bb * Cc * HWp / 256), dim3(256), 0, stream>>>(ybuf, x, stats, gamma, beta, out);
}

// Round 3
// 743.756 us; speedup vs baseline: 1.8811x; 1.8811x over previous
//
#include <hip/hip_runtime.h>
#include <math.h>

// Problem constants (B=4, C=64, H=W=192, K=3)
constexpr int Hh  = 192;
constexpr int Ww  = 192;
constexpr int HWp = Hh * Ww;      // 36864
constexpr int Cc  = 64;
constexpr int Bb  = 4;
constexpr int KK  = 9;
constexpr int OFFC = 18;          // 2*K*K
constexpr int PX  = 16;           // pixels per block in deform kernel

// ---------------- Kernel 1: 3x3 offset conv, one thread = one pixel, all 18 oc ----------------
// Weight index is wave-uniform -> scalar loads; each x-tap feeds 18 FMAs.
__global__ __launch_bounds__(256)
void k_offset_conv(const float* __restrict__ x, const float* __restrict__ Woff,
                   const float* __restrict__ boff, float* __restrict__ offset) {
    int idx = blockIdx.x * 256 + threadIdx.x;    // over B*HW
    int px = idx % HWp;
    int b  = idx / HWp;
    int h = px / Ww, w = px % Ww;
    float acc[OFFC];
    #pragma unroll
    for (int oc = 0; oc < OFFC; ++oc) acc[oc] = boff[oc];
    const float* xb = x + (size_t)b * Cc * HWp;
    for (int ic = 0; ic < Cc; ++ic) {
        const float* xp = xb + ic * HWp;
        float tap[9];
        #pragma unroll
        for (int t = 0; t < 9; ++t) {
            int yy = h + t / 3 - 1, xx = w + t % 3 - 1;
            bool ok = (yy >= 0 && yy < Hh && xx >= 0 && xx < Ww);
            tap[t] = ok ? xp[yy * Ww + xx] : 0.f;
        }
        #pragma unroll
        for (int t = 0; t < 9; ++t) {
            #pragma unroll
            for (int oc = 0; oc < OFFC; ++oc) {
                acc[oc] = fmaf(Woff[(oc * Cc + ic) * 9 + t], tap[t], acc[oc]);
            }
        }
    }
    #pragma unroll
    for (int oc = 0; oc < OFFC; ++oc)
        offset[((size_t)b * OFFC + oc) * HWp + px] = acc[oc];
}

// ---------------- Kernel 2: transpose weights for coalesced reads ----------------
__global__ __launch_bounds__(256)
void k_transpose(const float* __restrict__ Wd, const float* __restrict__ Wc,
                 float* __restrict__ WdT, float* __restrict__ WcT) {
    int i = blockIdx.x * 256 + threadIdx.x;
    if (i < Cc * Cc * KK) {                 // W_def [o][c*9+kk] -> [c*9+kk][o]
        int o = i / (Cc * KK), ck = i % (Cc * KK);
        WdT[ck * Cc + o] = Wd[i];
    }
    if (i < Cc * Cc) {                      // W_cat [o][c] -> [c][o]
        int o = i / Cc, c = i % Cc;
        WcT[c * Cc + o] = Wc[i];
    }
}

// ---------------- Kernel 3: deformable conv + 1x1 conv fused ----------------
__global__ __launch_bounds__(256)
void k_deform(const float* __restrict__ x, const float* __restrict__ offset,
              const float* __restrict__ WdT, const float* __restrict__ bdef,
              const float* __restrict__ WcT, const float* __restrict__ bcat,
              float* __restrict__ y) {
    __shared__ int   s_i00[KK * PX], s_i01[KK * PX], s_i10[KK * PX], s_i11[KK * PX];
    __shared__ float s_w00[KK * PX], s_w01[KK * PX], s_w10[KK * PX], s_w11[KK * PX];
    __shared__ float s_samp[Cc * KK * PX];   // [(c*9+kk)*PX + pxi]  ~36.9 KB
    __shared__ float s_y1[PX * Cc];          // [pxi*64 + c]

    const int t   = threadIdx.x;
    const int bpx = blockIdx.x % (HWp / PX);
    const int b   = blockIdx.x / (HWp / PX);
    const int px0 = bpx * PX;

    // Phase 0: bilinear params for 9 taps x 16 pixels
    if (t < KK * PX) {
        int pxi = t % PX, kk = t / PX;
        int px = px0 + pxi;
        int h = px / Ww, w = px % Ww;
        const float offy = offset[((size_t)b * OFFC + kk * 2    ) * HWp + px];
        const float offx = offset[((size_t)b * OFFC + kk * 2 + 1) * HWp + px];
        float py  = offy + (float)(h - 1 + kk / 3);
        float pxf = offx + (float)(w - 1 + kk % 3);
        float fy0 = floorf(py), fx0 = floorf(pxf);
        float wy = py - fy0, wx = pxf - fx0;
        int iy0 = (int)fy0, ix0 = (int)fx0;
        int iy1 = iy0 + 1,  ix1 = ix0 + 1;
        float v00 = (iy0 >= 0 && iy0 < Hh && ix0 >= 0 && ix0 < Ww) ? 1.f : 0.f;
        float v01 = (iy0 >= 0 && iy0 < Hh && ix1 >= 0 && ix1 < Ww) ? 1.f : 0.f;
        float v10 = (iy1 >= 0 && iy1 < Hh && ix0 >= 0 && ix0 < Ww) ? 1.f : 0.f;
        float v11 = (iy1 >= 0 && iy1 < Hh && ix1 >= 0 && ix1 < Ww) ? 1.f : 0.f;
        int cy0 = min(max(iy0, 0), Hh - 1), cy1 = min(max(iy1, 0), Hh - 1);
        int cx0 = min(max(ix0, 0), Ww - 1), cx1 = min(max(ix1, 0), Ww - 1);
        s_i00[t] = cy0 * Ww + cx0;  s_i01[t] = cy0 * Ww + cx1;
        s_i10[t] = cy1 * Ww + cx0;  s_i11[t] = cy1 * Ww + cx1;
        s_w00[t] = (1.f - wy) * (1.f - wx) * v00;
        s_w01[t] = (1.f - wy) * wx * v01;
        s_w10[t] = wy * (1.f - wx) * v10;
        s_w11[t] = wy * wx * v11;
    }
    __syncthreads();

    // Phase 1: bilinear sampling into LDS (64 ch x 9 taps x 16 px)
    const float* xb = x + (size_t)b * Cc * HWp;
    for (int i = t; i < Cc * KK * PX; i += 256) {
        int pxi = i & (PX - 1);
        int ckk = i >> 4;            // PX == 16
        int kk = ckk % KK;
        int c  = ckk / KK;
        int j  = kk * PX + pxi;
        const float* xp = xb + c * HWp;
        float v = s_w00[j] * xp[s_i00[j]] + s_w01[j] * xp[s_i01[j]]
                + s_w10[j] * xp[s_i10[j]] + s_w11[j] * xp[s_i11[j]];
        s_samp[i] = v;
    }
    __syncthreads();

    // Phase 2: deform contraction  y1[px][o] = sum_ck samp[ck][px] * WdT[ck][o]
    const int o  = t & 63;
    const int pg = t >> 6;           // 0..3, each handles 4 pixels
    float bv = bdef[o];
    float a0 = bv, a1 = bv, a2 = bv, a3 = bv;
    #pragma unroll 4
    for (int ck = 0; ck < Cc * KK; ++ck) {
        float wv = WdT[ck * Cc + o];
        float4 sv = *reinterpret_cast<const float4*>(&s_samp[ck * PX + pg * 4]);
        a0 = fmaf(wv, sv.x, a0);
        a1 = fmaf(wv, sv.y, a1);
        a2 = fmaf(wv, sv.z, a2);
        a3 = fmaf(wv, sv.w, a3);
    }
    s_y1[(pg * 4 + 0) * Cc + o] = a0;
    s_y1[(pg * 4 + 1) * Cc + o] = a1;
    s_y1[(pg * 4 + 2) * Cc + o] = a2;
    s_y1[(pg * 4 + 3) * Cc + o] = a3;
    __syncthreads();

    // Phase 3: 1x1 conv  y[px][o] = sum_c y1[px][c] * WcT[c][o] + bcat[o]
    float z0 = 0.f, z1 = 0.f, z2 = 0.f, z3 = 0.f;
    #pragma unroll 8
    for (int c = 0; c < Cc; ++c) {
        float wv = WcT[c * Cc + o];
        z0 = fmaf(wv, s_y1[(pg * 4 + 0) * Cc + c], z0);
        z1 = fmaf(wv, s_y1[(pg * 4 + 1) * Cc + c], z1);
        z2 = fmaf(wv, s_y1[(pg * 4 + 2) * Cc + c], z2);
        z3 = fmaf(wv, s_y1[(pg * 4 + 3) * Cc + c], z3);
    }
    float bc = bcat[o];
    size_t base = ((size_t)(b * Cc + o)) * HWp + px0 + pg * 4;
    y[base + 0] = z0 + bc;
    y[base + 1] = z1 + bc;
    y[base + 2] = z2 + bc;
    y[base + 3] = z3 + bc;
}

// ---------------- Kernel 4a: per-(b,c) partial stats (256 blocks) ----------------
__global__ __launch_bounds__(256)
void k_stats_partial(const float* __restrict__ y, double* __restrict__ part) {
    int bc = blockIdx.x;              // b*64 + c
    const float* yp = y + (size_t)bc * HWp;
    double s1 = 0.0, s2 = 0.0;
    for (int p = threadIdx.x; p < HWp; p += 256) {
        float v = yp[p];
        s1 += (double)v;
        s2 += (double)v * (double)v;
    }
    for (int d = 32; d >= 1; d >>= 1) {
        s1 += __shfl_down(s1, d);
        s2 += __shfl_down(s2, d);
    }
    __shared__ double r1[4], r2[4];
    int wv = threadIdx.x >> 6, ln = threadIdx.x & 63;
    if (ln == 0) { r1[wv] = s1; r2[wv] = s2; }
    __syncthreads();
    if (threadIdx.x == 0) {
        part[2 * bc]     = r1[0] + r1[1] + r1[2] + r1[3];
        part[2 * bc + 1] = r2[0] + r2[1] + r2[2] + r2[3];
    }
}

// ---------------- Kernel 4b: combine partials -> mean/invstd ----------------
__global__ __launch_bounds__(64)
void k_stats_final(const double* __restrict__ part, float* __restrict__ stats) {
    int c = threadIdx.x;              // 64 threads
    double t1 = 0.0, t2 = 0.0;
    for (int b = 0; b < Bb; ++b) {
        t1 += part[2 * (b * Cc + c)];
        t2 += part[2 * (b * Cc + c) + 1];
    }
    double n = (double)(Bb * HWp);
    double mean = t1 / n;
    double var  = t2 / n - mean * mean;
    stats[c]      = (float)mean;
    stats[Cc + c] = (float)(1.0 / sqrt(var + 1e-5));
}

// ---------------- Kernel 5: BN apply + ReLU + residual (float4) ----------------
__global__ __launch_bounds__(256)
void k_apply(const float4* __restrict__ y, const float4* __restrict__ x,
             const float* __restrict__ stats, const float* __restrict__ gamma,
             const float* __restrict__ beta, float4* __restrict__ out) {
    int idx = blockIdx.x * 256 + threadIdx.x;           // over B*C*HW/4
    int c = (idx / (HWp / 4)) % Cc;
    float mean = stats[c], inv = stats[Cc + c];
    float g = gamma[c], bt = beta[c];
    float4 yv = y[idx], xv = x[idx], o;
    o.x = fmaxf(g * ((yv.x - mean) * inv) + bt, 0.f) + xv.x;
    o.y = fmaxf(g * ((yv.y - mean) * inv) + bt, 0.f) + xv.y;
    o.z = fmaxf(g * ((yv.z - mean) * inv) + bt, 0.f) + xv.z;
    o.w = fmaxf(g * ((yv.w - mean) * inv) + bt, 0.f) + xv.w;
    out[idx] = o;
}

extern "C" void kernel_launch(void* const* d_in, const int* in_sizes, int n_in,
                              void* d_out, int out_size, void* d_ws, size_t ws_size,
                              hipStream_t stream) {
    const float* x     = (const float*)d_in[0];
    const float* Woff  = (const float*)d_in[1];
    const float* boff  = (const float*)d_in[2];
    const float* Wdef  = (const float*)d_in[3];
    const float* bdef  = (const float*)d_in[4];
    const float* Wcat  = (const float*)d_in[5];
    const float* bcat  = (const float*)d_in[6];
    const float* gamma = (const float*)d_in[7];
    const float* beta  = (const float*)d_in[8];
    float* out = (float*)d_out;

    float* ws     = (float*)d_ws;
    float* offset = ws;                               // B*18*HW   = 2,654,208 floats
    float* ybuf   = offset + (size_t)Bb * OFFC * HWp; // B*64*HW   = 9,437,184
    float* WdT    = ybuf + (size_t)Bb * Cc * HWp;     // 36,864
    float* WcT    = WdT + Cc * Cc * KK;               // 4,096
    float* stats  = WcT + Cc * Cc;                    // 128
    double* part  = (double*)(stats + 128);           // 256*2 doubles (8B-aligned: even float count)

    k_offset_conv<<<dim3(Bb * HWp / 256), dim3(256), 0, stream>>>(x, Woff, boff, offset);
    k_transpose<<<dim3((Cc * Cc * KK + 255) / 256), dim3(256), 0, stream>>>(Wdef, Wcat, WdT, WcT);
    k_deform<<<dim3(Bb * (HWp / PX)), dim3(256), 0, stream>>>(x, offset, WdT, bdef, WcT, bcat, ybuf);
    k_stats_partial<<<dim3(Bb * Cc), dim3(256), 0, stream>>>(ybuf, part);
    k_stats_final<<<dim3(1), dim3(64), 0, stream>>>(part, stats);
    k_apply<<<dim3(Bb * Cc * HWp / 4 / 256), dim3(256), 0, stream>>>(
        (const float4*)ybuf, (const float4*)x, stats, gamma, beta, (float4*)out);
}

// Round 4
// 456.946 us; speedup vs baseline: 3.0618x; 1.6277x over previous
//
#include <hip/hip_runtime.h>
#include <math.h>

// Problem constants (B=4, C=64, H=W=192, K=3)
constexpr int Hh  = 192;
constexpr int Ww  = 192;
constexpr int HWp = Hh * Ww;      // 36864
constexpr int Cc  = 64;
constexpr int Bb  = 4;
constexpr int KK  = 9;
constexpr int OFFC = 18;          // 2*K*K
constexpr int PXB = 32;           // pixels per deform block (divides Ww)
constexpr int NBPX = HWp / PXB;   // 1152 tiles per batch image
constexpr int KSD = (Cc * KK) / 32;  // 18 K-steps for deform GEMM (K=576)
constexpr int KSC = Cc / 32;         // 2  K-steps for 1x1 GEMM (K=64)

using bf16x8 = __attribute__((ext_vector_type(8))) short;  // 8 bf16 (4 VGPRs)
using f32x4  = __attribute__((ext_vector_type(4))) float;

static __device__ __forceinline__ unsigned short f2bf(float f) {
    unsigned int u = __float_as_uint(f);
    u += 0x7fff + ((u >> 16) & 1);       // round-to-nearest-even
    return (unsigned short)(u >> 16);
}

// ---------------- Kernel 1: 3x3 offset conv, one thread = one pixel, all 18 oc ----------------
__global__ __launch_bounds__(256)
void k_offset_conv(const float* __restrict__ x, const float* __restrict__ Woff,
                   const float* __restrict__ boff, float* __restrict__ offset) {
    int idx = blockIdx.x * 256 + threadIdx.x;    // over B*HW
    int px = idx % HWp;
    int b  = idx / HWp;
    int h = px / Ww, w = px % Ww;
    float acc[OFFC];
    #pragma unroll
    for (int oc = 0; oc < OFFC; ++oc) acc[oc] = boff[oc];
    const float* xb = x + (size_t)b * Cc * HWp;
    for (int ic = 0; ic < Cc; ++ic) {
        const float* xp = xb + ic * HWp;
        float tap[9];
        #pragma unroll
        for (int t = 0; t < 9; ++t) {
            int yy = h + t / 3 - 1, xx = w + t % 3 - 1;
            bool ok = (yy >= 0 && yy < Hh && xx >= 0 && xx < Ww);
            tap[t] = ok ? xp[yy * Ww + xx] : 0.f;
        }
        #pragma unroll
        for (int t = 0; t < 9; ++t) {
            #pragma unroll
            for (int oc = 0; oc < OFFC; ++oc) {
                acc[oc] = fmaf(Woff[(oc * Cc + ic) * 9 + t], tap[t], acc[oc]);
            }
        }
    }
    #pragma unroll
    for (int oc = 0; oc < OFFC; ++oc)
        offset[((size_t)b * OFFC + oc) * HWp + px] = acc[oc];
}

// ---------------- Kernel 2: pack W_def / W_cat into MFMA B-fragment order (bf16) ----------------
// B-frag for mfma_f32_16x16x32_bf16: lane l, reg r holds B[k = ks*32 + (l>>4)*8 + r][n = ot*16 + (l&15)]
// Fd layout: [ot(4)][ks(18)][lane(64)][r(8)];  Fc: [ot(4)][ks(2)][lane(64)][r(8)]
__global__ __launch_bounds__(256)
void k_wprep(const float* __restrict__ Wdef, const float* __restrict__ Wcat,
             unsigned short* __restrict__ Fd, unsigned short* __restrict__ Fc) {
    int i = blockIdx.x * 256 + threadIdx.x;
    if (i < 4 * KSD * 64 * 8) {
        int r = i & 7, lane = (i >> 3) & 63, ks = (i >> 9) % KSD, ot = (i >> 9) / KSD;
        int o  = ot * 16 + (lane & 15);
        int ck = ks * 32 + ((lane >> 4) << 3) + r;       // ck = c*9+kk
        Fd[i] = f2bf(Wdef[o * (Cc * KK) + ck]);
    }
    int j = i - 4 * KSD * 64 * 8;
    if (j >= 0 && j < 4 * KSC * 64 * 8) {
        int r = j & 7, lane = (j >> 3) & 63, ks = (j >> 9) & 1, ot = j >> 10;
        int o = ot * 16 + (lane & 15);
        int c = ks * 32 + ((lane >> 4) << 3) + r;
        Fc[j] = f2bf(Wcat[o * Cc + c]);
    }
}

// ---------------- Kernel 3: deformable conv + 1x1 conv, bf16 MFMA ----------------
__global__ __launch_bounds__(256)
void k_deform(const float* __restrict__ x, const float* __restrict__ offset,
              const unsigned short* __restrict__ Fd, const float* __restrict__ bdef,
              const unsigned short* __restrict__ Fc, const float* __restrict__ bcat,
              float* __restrict__ y) {
    // samp tile [32 px][576 ck] bf16, XOR-swizzled; aliased by epilogue s_out fp32[64 oc][32 px]
    __shared__ __align__(16) unsigned char s_buf[PXB * Cc * KK * 2];   // 36864 B
    __shared__ __align__(16) unsigned char s_y1[PXB * Cc * 2];         // 4096 B, y1 bf16 swizzled
    __shared__ int   s_idx[4][KK * PXB];
    __shared__ float s_wgt[4][KK * PXB];

    const int t = threadIdx.x;
    int wg = blockIdx.x;
    wg = (wg & 7) * (Bb * NBPX / 8) + (wg >> 3);   // XCD swizzle (4608 % 8 == 0 -> bijective)
    const int b   = wg / NBPX;
    const int px0 = (wg % NBPX) * PXB;
    const int h   = px0 / Ww;                      // uniform: PXB divides Ww
    const int w0  = px0 % Ww;

    // Phase 0: bilinear params for 9 taps x 32 pixels
    for (int i = t; i < KK * PXB; i += 256) {
        int kk = i >> 5, pxl = i & 31;
        float offy = offset[((size_t)b * OFFC + kk * 2    ) * HWp + px0 + pxl];
        float offx = offset[((size_t)b * OFFC + kk * 2 + 1) * HWp + px0 + pxl];
        float py  = offy + (float)(h - 1 + kk / 3);
        float pxf = offx + (float)(w0 + pxl - 1 + kk % 3);
        float fy0 = floorf(py), fx0 = floorf(pxf);
        float wy = py - fy0, wx = pxf - fx0;
        int iy0 = (int)fy0, ix0 = (int)fx0, iy1 = iy0 + 1, ix1 = ix0 + 1;
        float v00 = (iy0 >= 0 && iy0 < Hh && ix0 >= 0 && ix0 < Ww) ? 1.f : 0.f;
        float v01 = (iy0 >= 0 && iy0 < Hh && ix1 >= 0 && ix1 < Ww) ? 1.f : 0.f;
        float v10 = (iy1 >= 0 && iy1 < Hh && ix0 >= 0 && ix0 < Ww) ? 1.f : 0.f;
        float v11 = (iy1 >= 0 && iy1 < Hh && ix1 >= 0 && ix1 < Ww) ? 1.f : 0.f;
        int cy0 = min(max(iy0, 0), Hh - 1), cy1 = min(max(iy1, 0), Hh - 1);
        int cx0 = min(max(ix0, 0), Ww - 1), cx1 = min(max(ix1, 0), Ww - 1);
        s_idx[0][i] = cy0 * Ww + cx0;  s_idx[1][i] = cy0 * Ww + cx1;
        s_idx[2][i] = cy1 * Ww + cx0;  s_idx[3][i] = cy1 * Ww + cx1;
        s_wgt[0][i] = (1.f - wy) * (1.f - wx) * v00;
        s_wgt[1][i] = (1.f - wy) * wx * v01;
        s_wgt[2][i] = wy * (1.f - wx) * v10;
        s_wgt[3][i] = wy * wx * v11;
    }
    __syncthreads();

    // Phase 1: bilinear sampling -> swizzled bf16 samp tile
    const float* xb = x + (size_t)b * Cc * HWp;
    for (int i = t; i < KK * PXB; i += 256) {
        int kk = i >> 5, pxl = i & 31;
        int i00 = s_idx[0][i], i01 = s_idx[1][i], i10 = s_idx[2][i], i11 = s_idx[3][i];
        float w00 = s_wgt[0][i], w01 = s_wgt[1][i], w10 = s_wgt[2][i], w11 = s_wgt[3][i];
        unsigned rowb = (unsigned)pxl * (Cc * KK * 2);
        unsigned swz  = (unsigned)(pxl & 7) << 4;
        const float* xp = xb;
        #pragma unroll 4
        for (int c = 0; c < Cc; ++c) {
            float v = w00 * xp[i00] + w01 * xp[i01] + w10 * xp[i10] + w11 * xp[i11];
            unsigned col = (unsigned)(c * KK + kk) * 2;
            *(unsigned short*)(s_buf + rowb + (col ^ swz)) = f2bf(v);
            xp += HWp;
        }
    }
    __syncthreads();

    // Phase 2: deform GEMM  y1[32px][64o] = samp[32px][576] @ Wdef^T[576][64]
    const int lane  = t & 63;
    const int ot    = t >> 6;            // wave -> oc tile
    const int klane = lane >> 4;         // 0..3
    const unsigned swzA = (unsigned)(lane & 7) << 4;
    const unsigned rA0  = (unsigned)(lane & 15) * (Cc * KK * 2);
    const unsigned rA1  = rA0 + 16u * (Cc * KK * 2);
    f32x4 acc0 = {0.f, 0.f, 0.f, 0.f}, acc1 = {0.f, 0.f, 0.f, 0.f};
    const bf16x8* Bd = (const bf16x8*)Fd + (size_t)ot * KSD * 64;
    #pragma unroll 3
    for (int ks = 0; ks < KSD; ++ks) {
        unsigned cb = ((unsigned)(ks * 64 + klane * 16)) ^ swzA;
        bf16x8 a0 = *(const bf16x8*)(s_buf + rA0 + cb);
        bf16x8 a1 = *(const bf16x8*)(s_buf + rA1 + cb);
        bf16x8 bd = Bd[ks * 64 + lane];
        acc0 = __builtin_amdgcn_mfma_f32_16x16x32_bf16(a0, bd, acc0, 0, 0, 0);
        acc1 = __builtin_amdgcn_mfma_f32_16x16x32_bf16(a1, bd, acc1, 0, 0, 0);
    }

    // Write y1 (+ b_def) as swizzled bf16 for the 1x1 GEMM's A operand
    const int o = ot * 16 + (lane & 15);
    {
        float bv = bdef[o];
        unsigned colb = (unsigned)o * 2;
        #pragma unroll
        for (int r = 0; r < 4; ++r) {
            int row0 = klane * 4 + r;            // rows 0..15 (px tile 0)
            int row1 = row0 + 16;                // px tile 1; (row1&7)==(row0&7)
            unsigned sw = (unsigned)(row0 & 7) << 4;
            *(unsigned short*)(s_y1 + row0 * (Cc * 2) + (colb ^ sw)) = f2bf(acc0[r] + bv);
            *(unsigned short*)(s_y1 + row1 * (Cc * 2) + (colb ^ sw)) = f2bf(acc1[r] + bv);
        }
    }
    __syncthreads();

    // Phase 3: 1x1 GEMM  yout[32px][64o] = y1[32px][64c] @ Wcat^T[64][64]
    f32x4 c0 = {0.f, 0.f, 0.f, 0.f}, c1 = {0.f, 0.f, 0.f, 0.f};
    const bf16x8* Bc = (const bf16x8*)Fc + (size_t)ot * KSC * 64;
    const unsigned rY0 = (unsigned)(lane & 15) * (Cc * 2);
    const unsigned rY1 = rY0 + 16u * (Cc * 2);
    #pragma unroll
    for (int ks = 0; ks < KSC; ++ks) {
        unsigned cb = ((unsigned)(ks * 64 + klane * 16)) ^ swzA;
        bf16x8 a0 = *(const bf16x8*)(s_y1 + rY0 + cb);
        bf16x8 a1 = *(const bf16x8*)(s_y1 + rY1 + cb);
        bf16x8 bc = Bc[ks * 64 + lane];
        c0 = __builtin_amdgcn_mfma_f32_16x16x32_bf16(a0, bc, c0, 0, 0, 0);
        c1 = __builtin_amdgcn_mfma_f32_16x16x32_bf16(a1, bc, c1, 0, 0, 0);
    }

    // Epilogue: transpose via LDS (aliases dead samp buffer) -> coalesced float4 stores
    // s_out fp32 [64 o][32 px], row 128B, swizzle ^((o&7)<<4)
    {
        float bcv = bcat[o];
        unsigned orow = (unsigned)o * (PXB * 4);
        unsigned sw   = (unsigned)(o & 7) << 4;
        #pragma unroll
        for (int r = 0; r < 4; ++r) {
            int p0 = klane * 4 + r, p1 = p0 + 16;
            *(float*)(s_buf + orow + (((unsigned)p0 * 4) ^ sw)) = c0[r] + bcv;
            *(float*)(s_buf + orow + (((unsigned)p1 * 4) ^ sw)) = c1[r] + bcv;
        }
    }
    __syncthreads();
    float* yb = y + (size_t)b * Cc * HWp + px0;
    #pragma unroll
    for (int it = 0; it < 2; ++it) {
        int oo = it * 32 + (t >> 3), pxq = t & 7;
        float4 v = *(const float4*)(s_buf + (unsigned)oo * (PXB * 4)
                                    + (((unsigned)pxq * 16) ^ ((unsigned)(oo & 7) << 4)));
        *(float4*)(yb + (size_t)oo * HWp + pxq * 4) = v;
    }
}

// ---------------- Kernel 4a: per-(b,c) partial stats (256 blocks) ----------------
__global__ __launch_bounds__(256)
void k_stats_partial(const float* __restrict__ y, double* __restrict__ part) {
    int bc = blockIdx.x;              // b*64 + c
    const float* yp = y + (size_t)bc * HWp;
    double s1 = 0.0, s2 = 0.0;
    for (int p = threadIdx.x; p < HWp; p += 256) {
        float v = yp[p];
        s1 += (double)v;
        s2 += (double)v * (double)v;
    }
    for (int d = 32; d >= 1; d >>= 1) {
        s1 += __shfl_down(s1, d);
        s2 += __shfl_down(s2, d);
    }
    __shared__ double r1[4], r2[4];
    int wv = threadIdx.x >> 6, ln = threadIdx.x & 63;
    if (ln == 0) { r1[wv] = s1; r2[wv] = s2; }
    __syncthreads();
    if (threadIdx.x == 0) {
        part[2 * bc]     = r1[0] + r1[1] + r1[2] + r1[3];
        part[2 * bc + 1] = r2[0] + r2[1] + r2[2] + r2[3];
    }
}

// ---------------- Kernel 4b: combine partials -> mean/invstd ----------------
__global__ __launch_bounds__(64)
void k_stats_final(const double* __restrict__ part, float* __restrict__ stats) {
    int c = threadIdx.x;              // 64 threads
    double t1 = 0.0, t2 = 0.0;
    for (int b = 0; b < Bb; ++b) {
        t1 += part[2 * (b * Cc + c)];
        t2 += part[2 * (b * Cc + c) + 1];
    }
    double n = (double)(Bb * HWp);
    double mean = t1 / n;
    double var  = t2 / n - mean * mean;
    stats[c]      = (float)mean;
    stats[Cc + c] = (float)(1.0 / sqrt(var + 1e-5));
}

// ---------------- Kernel 5: BN apply + ReLU + residual (float4) ----------------
__global__ __launch_bounds__(256)
void k_apply(const float4* __restrict__ y, const float4* __restrict__ x,
             const float* __restrict__ stats, const float* __restrict__ gamma,
             const float* __restrict__ beta, float4* __restrict__ out) {
    int idx = blockIdx.x * 256 + threadIdx.x;           // over B*C*HW/4
    int c = (idx / (HWp / 4)) % Cc;
    float mean = stats[c], inv = stats[Cc + c];
    float g = gamma[c], bt = beta[c];
    float4 yv = y[idx], xv = x[idx], o;
    o.x = fmaxf(g * ((yv.x - mean) * inv) + bt, 0.f) + xv.x;
    o.y = fmaxf(g * ((yv.y - mean) * inv) + bt, 0.f) + xv.y;
    o.z = fmaxf(g * ((yv.z - mean) * inv) + bt, 0.f) + xv.z;
    o.w = fmaxf(g * ((yv.w - mean) * inv) + bt, 0.f) + xv.w;
    out[idx] = o;
}

extern "C" void kernel_launch(void* const* d_in, const int* in_sizes, int n_in,
                              void* d_out, int out_size, void* d_ws, size_t ws_size,
                              hipStream_t stream) {
    const float* x     = (const float*)d_in[0];
    const float* Woff  = (const float*)d_in[1];
    const float* boff  = (const float*)d_in[2];
    const float* Wdef  = (const float*)d_in[3];
    const float* bdef  = (const float*)d_in[4];
    const float* Wcat  = (const float*)d_in[5];
    const float* bcat  = (const float*)d_in[6];
    const float* gamma = (const float*)d_in[7];
    const float* beta  = (const float*)d_in[8];
    float* out = (float*)d_out;

    float* ws     = (float*)d_ws;
    float* offset = ws;                                // B*18*HW = 2,654,208 floats
    float* ybuf   = offset + (size_t)Bb * OFFC * HWp;  // B*64*HW = 9,437,184 floats
    float* stats  = ybuf + (size_t)Bb * Cc * HWp;      // 128 floats
    double* part  = (double*)(stats + 128);            // 512 doubles (8B aligned)
    unsigned short* Fd = (unsigned short*)(part + 512);   // 36,864 u16 (16B aligned)
    unsigned short* Fc = Fd + 4 * KSD * 64 * 8;           // 4,096 u16

    k_offset_conv<<<dim3(Bb * HWp / 256), dim3(256), 0, stream>>>(x, Woff, boff, offset);
    k_wprep<<<dim3((4 * KSD * 64 * 8 + 4 * KSC * 64 * 8) / 256), dim3(256), 0, stream>>>(Wdef, Wcat, Fd, Fc);
    k_deform<<<dim3(Bb * NBPX), dim3(256), 0, stream>>>(x, offset, Fd, bdef, Fc, bcat, ybuf);
    k_stats_partial<<<dim3(Bb * Cc), dim3(256), 0, stream>>>(ybuf, part);
    k_stats_final<<<dim3(1), dim3(64), 0, stream>>>(part, stats);
    k_apply<<<dim3(Bb * Cc * HWp / 4 / 256), dim3(256), 0, stream>>>(
        (const float4*)ybuf, (const float4*)x, stats, gamma, beta, (float4*)out);
}

// Round 6
// 350.505 us; speedup vs baseline: 3.9917x; 1.3037x over previous
//
#include <hip/hip_runtime.h>
#include <math.h>

// Problem constants (B=4, C=64, H=W=192, K=3)
constexpr int Hh  = 192;
constexpr int Ww  = 192;
constexpr int HWp = Hh * Ww;      // 36864
constexpr int Cc  = 64;
constexpr int Bb  = 4;
constexpr int KK  = 9;
constexpr int OFFC = 18;          // 2*K*K
constexpr int PXB = 32;           // pixels per fused block (divides Ww)
constexpr int NBPX = HWp / PXB;   // 1152 tiles per batch image
constexpr int KSD = (Cc * KK) / 32;  // 18 K-steps, K=576
constexpr int KSC = Cc / 32;         // 2  K-steps, K=64

using bf16x8 = __attribute__((ext_vector_type(8))) short;  // 8 bf16 (4 VGPRs)
using f32x4  = __attribute__((ext_vector_type(4))) float;

static __device__ __forceinline__ unsigned short f2bf(float f) {
    unsigned int u = __float_as_uint(f);
    u += 0x7fff + ((u >> 16) & 1);       // round-to-nearest-even
    return (unsigned short)(u >> 16);
}
static __device__ __forceinline__ float bf2f(unsigned short u) {
    return __uint_as_float((unsigned)u << 16);
}

// ---------------- Kernel 1: x NCHW f32 -> channels-last bf16 [B][HW][64c] ----------------
__global__ __launch_bounds__(256)
void k_xpose(const float* __restrict__ x, unsigned short* __restrict__ xcl) {
    __shared__ unsigned short tile[64][66];   // pad 2 -> 33-word row stride, conflict-free transpose
    int b   = blockIdx.x / (HWp / 64);
    int px0 = (blockIdx.x % (HWp / 64)) * 64;
    int t = threadIdx.x;
    #pragma unroll
    for (int r = 0; r < 16; ++r) {
        int c = r * 4 + (t >> 6), pxl = t & 63;
        tile[c][pxl] = f2bf(x[((size_t)b * Cc + c) * HWp + px0 + pxl]);
    }
    __syncthreads();
    #pragma unroll
    for (int r = 0; r < 16; ++r) {
        int pxl = r * 4 + (t >> 6), c = t & 63;
        xcl[((size_t)b * HWp + px0 + pxl) * Cc + c] = tile[c][pxl];
    }
}

// ---------------- Kernel 2: pack W_def / W_cat / W_off into MFMA B-fragment order (bf16) ----------------
// B-frag (16x16x32): lane l, reg r holds B[k = ks*32 + (l>>4)*8 + r][n = ot*16 + (l&15)]
__global__ __launch_bounds__(256)
void k_wprep(const float* __restrict__ Wdef, const float* __restrict__ Wcat,
             const float* __restrict__ Woff,
             unsigned short* __restrict__ Fd, unsigned short* __restrict__ Fc,
             unsigned short* __restrict__ Fo) {
    int i = blockIdx.x * 256 + threadIdx.x;
    if (i < 4 * KSD * 64 * 8) {                       // Fd: [ot4][ks18][lane][r]
        int r = i & 7, lane = (i >> 3) & 63, ks = (i >> 9) % KSD, ot = (i >> 9) / KSD;
        int o  = ot * 16 + (lane & 15);
        int ck = ks * 32 + ((lane >> 4) << 3) + r;
        Fd[i] = f2bf(Wdef[o * (Cc * KK) + ck]);
    }
    int j = i - 4 * KSD * 64 * 8;
    if (j >= 0 && j < 4 * KSC * 64 * 8) {             // Fc: [ot4][ks2][lane][r]
        int r = j & 7, lane = (j >> 3) & 63, ks = (j >> 9) & 1, ot = j >> 10;
        int o = ot * 16 + (lane & 15);
        int c = ks * 32 + ((lane >> 4) << 3) + r;
        Fc[j] = f2bf(Wcat[o * Cc + c]);
    }
    int m = j - 4 * KSC * 64 * 8;
    if (m >= 0 && m < 2 * KSD * 64 * 8) {             // Fo: [ot2][ks18][lane][r], oc>=18 zero-padded
        int r = m & 7, lane = (m >> 3) & 63, ks = (m >> 9) % KSD, ot = (m >> 9) / KSD;
        int o  = ot * 16 + (lane & 15);
        int ck = ks * 32 + ((lane >> 4) << 3) + r;
        Fo[m] = (o < OFFC) ? f2bf(Woff[o * (Cc * KK) + ck]) : 0;
    }
}

// ---------------- Kernel 3: FUSED offset-conv + deformable conv + 1x1 conv ----------------
__global__ __launch_bounds__(256)
void k_fused(const unsigned short* __restrict__ xcl,
             const unsigned short* __restrict__ Fo, const float* __restrict__ boff,
             const unsigned short* __restrict__ Fd, const float* __restrict__ bdef,
             const unsigned short* __restrict__ Fc, const float* __restrict__ bcat,
             float* __restrict__ y) {
    // s_buf: bf16 [32 px][576 ck] swizzled (taps, then bilinear samples); aliased fp32[64 o][32 px] in epilogue
    __shared__ __align__(16) unsigned char s_buf[PXB * Cc * KK * 2];   // 36864 B
    __shared__ __align__(16) unsigned char s_y1[PXB * Cc * 2];         // 4096 B
    __shared__ float s_off[PXB][OFFC];                                 // 2304 B

    const int t = threadIdx.x;
    const int lane = t & 63, wv = t >> 6;
    const int klane = lane >> 4;
    int wg = blockIdx.x;
    wg = (wg & 7) * (Bb * NBPX / 8) + (wg >> 3);   // XCD swizzle (4608 % 8 == 0 -> bijective)
    const int b   = wg / NBPX;
    const int px0 = (wg % NBPX) * PXB;
    const int h   = px0 / Ww;                      // uniform: PXB divides Ww
    const int w0  = px0 % Ww;
    const unsigned short* xb = xcl + (size_t)b * HWp * Cc;

    // ---- P0: plain 3x3 taps (zero-padded) -> s_buf; lane = channel, coalesced 128B loads
    #pragma unroll
    for (int kk = 0; kk < KK; ++kk) {
        int row = h + kk / 3 - 1;
        bool rok = (row >= 0 && row < Hh);
        #pragma unroll
        for (int p = 0; p < 8; ++p) {
            int pxl = wv * 8 + p;
            int col = w0 + pxl + kk % 3 - 1;
            unsigned short u = 0;
            if (rok && col >= 0 && col < Ww)
                u = xb[(size_t)(row * Ww + col) * Cc + lane];
            unsigned addr = (unsigned)pxl * (Cc * KK * 2)
                          + ((((unsigned)(lane * KK + kk)) * 2) ^ ((unsigned)(pxl & 7) << 4));
            *(unsigned short*)(s_buf + addr) = u;
        }
    }
    __syncthreads();

    // ---- P0-MFMA: offsets[32px][18oc] = taps @ Woff^T ; waves: (oc-tile, px-tile)
    {
        const int pxt = wv & 1, oto = wv >> 1;
        const unsigned swzA = (unsigned)(lane & 7) << 4;
        const unsigned rA = ((unsigned)(lane & 15) + (unsigned)pxt * 16) * (Cc * KK * 2);
        f32x4 a = {0.f, 0.f, 0.f, 0.f};
        const bf16x8* Bo = (const bf16x8*)Fo + (size_t)oto * KSD * 64;
        #pragma unroll 3
        for (int ks = 0; ks < KSD; ++ks) {
            unsigned cb = ((unsigned)(ks * 64 + klane * 16)) ^ swzA;
            bf16x8 af = *(const bf16x8*)(s_buf + rA + cb);
            a = __builtin_amdgcn_mfma_f32_16x16x32_bf16(af, Bo[ks * 64 + lane], a, 0, 0, 0);
        }
        int oc = oto * 16 + (lane & 15);
        if (oc < OFFC) {
            float bv = boff[oc];
            #pragma unroll
            for (int r = 0; r < 4; ++r)
                s_off[pxt * 16 + klane * 4 + r][oc] = a[r] + bv;
        }
    }
    __syncthreads();

    // ---- P1: bilinear gather (channels-last) -> s_buf overwrite
    #pragma unroll
    for (int kk = 0; kk < KK; ++kk) {
        float fky = (float)(h - 1 + kk / 3);
        float fkx = (float)(w0 - 1 + kk % 3);
        #pragma unroll 2
        for (int p = 0; p < 8; ++p) {
            int pxl = wv * 8 + p;
            float py  = s_off[pxl][kk * 2]     + fky;
            float pxf = s_off[pxl][kk * 2 + 1] + fkx + (float)pxl;
            float fy0 = floorf(py), fx0 = floorf(pxf);
            float wy = py - fy0, wx = pxf - fx0;
            int iy0 = (int)fy0, ix0 = (int)fx0, iy1 = iy0 + 1, ix1 = ix0 + 1;
            float v00 = (iy0 >= 0 && iy0 < Hh && ix0 >= 0 && ix0 < Ww) ? 1.f : 0.f;
            float v01 = (iy0 >= 0 && iy0 < Hh && ix1 >= 0 && ix1 < Ww) ? 1.f : 0.f;
            float v10 = (iy1 >= 0 && iy1 < Hh && ix0 >= 0 && ix0 < Ww) ? 1.f : 0.f;
            float v11 = (iy1 >= 0 && iy1 < Hh && ix1 >= 0 && ix1 < Ww) ? 1.f : 0.f;
            int cy0 = min(max(iy0, 0), Hh - 1), cy1 = min(max(iy1, 0), Hh - 1);
            int cx0 = min(max(ix0, 0), Ww - 1), cx1 = min(max(ix1, 0), Ww - 1);
            float w00 = (1.f - wy) * (1.f - wx) * v00;
            float w01 = (1.f - wy) * wx * v01;
            float w10 = wy * (1.f - wx) * v10;
            float w11 = wy * wx * v11;
            const unsigned short* p00 = xb + (size_t)(cy0 * Ww + cx0) * Cc + lane;
            const unsigned short* p01 = xb + (size_t)(cy0 * Ww + cx1) * Cc + lane;
            const unsigned short* p10 = xb + (size_t)(cy1 * Ww + cx0) * Cc + lane;
            const unsigned short* p11 = xb + (size_t)(cy1 * Ww + cx1) * Cc + lane;
            float v = w00 * bf2f(*p00) + w01 * bf2f(*p01)
                    + w10 * bf2f(*p10) + w11 * bf2f(*p11);
            unsigned addr = (unsigned)pxl * (Cc * KK * 2)
                          + ((((unsigned)(lane * KK + kk)) * 2) ^ ((unsigned)(pxl & 7) << 4));
            *(unsigned short*)(s_buf + addr) = f2bf(v);
        }
    }
    __syncthreads();

    // ---- P2: deform GEMM  y1[32px][64o] = samp[32px][576] @ Wdef^T
    const int ot = wv;
    const unsigned swzA = (unsigned)(lane & 7) << 4;
    const unsigned rA0  = (unsigned)(lane & 15) * (Cc * KK * 2);
    const unsigned rA1  = rA0 + 16u * (Cc * KK * 2);
    f32x4 acc0 = {0.f, 0.f, 0.f, 0.f}, acc1 = {0.f, 0.f, 0.f, 0.f};
    const bf16x8* Bd = (const bf16x8*)Fd + (size_t)ot * KSD * 64;
    #pragma unroll 3
    for (int ks = 0; ks < KSD; ++ks) {
        unsigned cb = ((unsigned)(ks * 64 + klane * 16)) ^ swzA;
        bf16x8 a0 = *(const bf16x8*)(s_buf + rA0 + cb);
        bf16x8 a1 = *(const bf16x8*)(s_buf + rA1 + cb);
        bf16x8 bd = Bd[ks * 64 + lane];
        acc0 = __builtin_amdgcn_mfma_f32_16x16x32_bf16(a0, bd, acc0, 0, 0, 0);
        acc1 = __builtin_amdgcn_mfma_f32_16x16x32_bf16(a1, bd, acc1, 0, 0, 0);
    }
    const int o = ot * 16 + (lane & 15);
    {
        float bv = bdef[o];
        unsigned colb = (unsigned)o * 2;
        #pragma unroll
        for (int r = 0; r < 4; ++r) {
            int row0 = klane * 4 + r, row1 = row0 + 16;
            unsigned sw = (unsigned)(row0 & 7) << 4;
            *(unsigned short*)(s_y1 + row0 * (Cc * 2) + (colb ^ sw)) = f2bf(acc0[r] + bv);
            *(unsigned short*)(s_y1 + row1 * (Cc * 2) + (colb ^ sw)) = f2bf(acc1[r] + bv);
        }
    }
    __syncthreads();

    // ---- P3: 1x1 GEMM  yout[32px][64o] = y1 @ Wcat^T
    f32x4 c0 = {0.f, 0.f, 0.f, 0.f}, c1 = {0.f, 0.f, 0.f, 0.f};
    const bf16x8* Bc = (const bf16x8*)Fc + (size_t)ot * KSC * 64;
    const unsigned rY0 = (unsigned)(lane & 15) * (Cc * 2);
    const unsigned rY1 = rY0 + 16u * (Cc * 2);
    #pragma unroll
    for (int ks = 0; ks < KSC; ++ks) {
        unsigned cb = ((unsigned)(ks * 64 + klane * 16)) ^ swzA;
        bf16x8 a0 = *(const bf16x8*)(s_y1 + rY0 + cb);
        bf16x8 a1 = *(const bf16x8*)(s_y1 + rY1 + cb);
        bf16x8 bc = Bc[ks * 64 + lane];
        c0 = __builtin_amdgcn_mfma_f32_16x16x32_bf16(a0, bc, c0, 0, 0, 0);
        c1 = __builtin_amdgcn_mfma_f32_16x16x32_bf16(a1, bc, c1, 0, 0, 0);
    }

    // ---- Epilogue: transpose via LDS (aliases s_buf) -> coalesced float4 stores
    __syncthreads();     // P2/P0 s_buf readers are past the s_y1 barrier; fence before overwrite
    {
        float bcv = bcat[o];
        unsigned orow = (unsigned)o * (PXB * 4);
        unsigned sw   = (unsigned)(o & 7) << 4;
        #pragma unroll
        for (int r = 0; r < 4; ++r) {
            int p0 = klane * 4 + r, p1 = p0 + 16;
            *(float*)(s_buf + orow + (((unsigned)p0 * 4) ^ sw)) = c0[r] + bcv;
            *(float*)(s_buf + orow + (((unsigned)p1 * 4) ^ sw)) = c1[r] + bcv;
        }
    }
    __syncthreads();
    float* yb = y + (size_t)b * Cc * HWp + px0;
    #pragma unroll
    for (int it = 0; it < 2; ++it) {
        int oo = it * 32 + (t >> 3), pxq = t & 7;
        float4 v = *(const float4*)(s_buf + (unsigned)oo * (PXB * 4)
                                    + (((unsigned)pxq * 16) ^ ((unsigned)(oo & 7) << 4)));
        *(float4*)(yb + (size_t)oo * HWp + pxq * 4) = v;
    }
}

// ---------------- Kernel 4a: per-(b,c) partial stats ----------------
__global__ __launch_bounds__(256)
void k_stats_partial(const float* __restrict__ y, double* __restrict__ part) {
    int bc = blockIdx.x;              // b*64 + c
    const float* yp = y + (size_t)bc * HWp;
    double s1 = 0.0, s2 = 0.0;
    for (int p = threadIdx.x; p < HWp; p += 256) {
        float v = yp[p];
        s1 += (double)v;
        s2 += (double)v * (double)v;
    }
    for (int d = 32; d >= 1; d >>= 1) {
        s1 += __shfl_down(s1, d);
        s2 += __shfl_down(s2, d);
    }
    __shared__ double r1[4], r2[4];
    int wv = threadIdx.x >> 6, ln = threadIdx.x & 63;
    if (ln == 0) { r1[wv] = s1; r2[wv] = s2; }
    __syncthreads();
    if (threadIdx.x == 0) {
        part[2 * bc]     = r1[0] + r1[1] + r1[2] + r1[3];
        part[2 * bc + 1] = r2[0] + r2[1] + r2[2] + r2[3];
    }
}

// ---------------- Kernel 4b: combine partials -> mean/invstd ----------------
__global__ __launch_bounds__(64)
void k_stats_final(const double* __restrict__ part, float* __restrict__ stats) {
    int c = threadIdx.x;              // 64 threads
    double t1 = 0.0, t2 = 0.0;
    for (int b = 0; b < Bb; ++b) {
        t1 += part[2 * (b * Cc + c)];
        t2 += part[2 * (b * Cc + c) + 1];
    }
    double n = (double)(Bb * HWp);
    double mean = t1 / n;
    double var  = t2 / n - mean * mean;
    stats[c]      = (float)mean;
    stats[Cc + c] = (float)(1.0 / sqrt(var + 1e-5));
}

// ---------------- Kernel 5: BN apply + ReLU + residual (float4) ----------------
__global__ __launch_bounds__(256)
void k_apply(const float4* __restrict__ y, const float4* __restrict__ x,
             const float* __restrict__ stats, const float* __restrict__ gamma,
             const float* __restrict__ beta, float4* __restrict__ out) {
    int idx = blockIdx.x * 256 + threadIdx.x;           // over B*C*HW/4
    int c = (idx / (HWp / 4)) % Cc;
    float mean = stats[c], inv = stats[Cc + c];
    float g = gamma[c], bt = beta[c];
    float4 yv = y[idx], xv = x[idx], o;
    o.x = fmaxf(g * ((yv.x - mean) * inv) + bt, 0.f) + xv.x;
    o.y = fmaxf(g * ((yv.y - mean) * inv) + bt, 0.f) + xv.y;
    o.z = fmaxf(g * ((yv.z - mean) * inv) + bt, 0.f) + xv.z;
    o.w = fmaxf(g * ((yv.w - mean) * inv) + bt, 0.f) + xv.w;
    out[idx] = o;
}

extern "C" void kernel_launch(void* const* d_in, const int* in_sizes, int n_in,
                              void* d_out, int out_size, void* d_ws, size_t ws_size,
                              hipStream_t stream) {
    const float* x     = (const float*)d_in[0];
    const float* Woff  = (const float*)d_in[1];
    const float* boff  = (const float*)d_in[2];
    const float* Wdef  = (const float*)d_in[3];
    const float* bdef  = (const float*)d_in[4];
    const float* Wcat  = (const float*)d_in[5];
    const float* bcat  = (const float*)d_in[6];
    const float* gamma = (const float*)d_in[7];
    const float* beta  = (const float*)d_in[8];
    float* out = (float*)d_out;

    float* ws    = (float*)d_ws;
    float* ybuf  = ws;                                  // 9,437,184 f32
    float* stats = ybuf + (size_t)Bb * Cc * HWp;        // 128 f32
    double* part = (double*)(stats + 128);              // 512 dbl (8B-aligned)
    unsigned short* Fd  = (unsigned short*)(part + 512);   // 36,864 u16 (16B-aligned)
    unsigned short* Fc  = Fd + 4 * KSD * 64 * 8;           // 4,096 u16
    unsigned short* Fo  = Fc + 4 * KSC * 64 * 8;           // 18,432 u16
    unsigned short* xcl = Fo + 2 * KSD * 64 * 8;           // 9,437,184 u16

    k_xpose<<<dim3(Bb * (HWp / 64)), dim3(256), 0, stream>>>(x, xcl);
    k_wprep<<<dim3((4 * KSD * 64 * 8 + 4 * KSC * 64 * 8 + 2 * KSD * 64 * 8 + 255) / 256),
              dim3(256), 0, stream>>>(Wdef, Wcat, Woff, Fd, Fc, Fo);
    k_fused<<<dim3(Bb * NBPX), dim3(256), 0, stream>>>(xcl, Fo, boff, Fd, bdef, Fc, bcat, ybuf);
    k_stats_partial<<<dim3(Bb * Cc), dim3(256), 0, stream>>>(ybuf, part);
    k_stats_final<<<dim3(1), dim3(64), 0, stream>>>(part, stats);
    k_apply<<<dim3(Bb * Cc * HWp / 4 / 256), dim3(256), 0, stream>>>(
        (const float4*)ybuf, (const float4*)x, stats, gamma, beta, (float4*)out);
}

// Round 7
// 217.452 us; speedup vs baseline: 6.4340x; 1.6119x over previous
//
#include <hip/hip_runtime.h>
#include <math.h>

// Problem constants (B=4, C=64, H=W=192, K=3)
constexpr int Hh  = 192;
constexpr int Ww  = 192;
constexpr int HWp = Hh * Ww;      // 36864
constexpr int Cc  = 64;
constexpr int Bb  = 4;
constexpr int KK  = 9;
constexpr int OFFC = 18;          // 2*K*K
constexpr int PXB = 32;           // pixels per fused block (divides Ww)
constexpr int NBPX = HWp / PXB;   // 1152 tiles per batch image
constexpr int KSD = (Cc * KK) / 32;  // 18 K-steps, K=576
constexpr int KSC = Cc / 32;         // 2  K-steps, K=64
constexpr int NIT = KK * PXB;        // 288 (tap,pixel) items per block
constexpr int SLOTS = 64;            // stats accumulation slots per channel

using bf16x8 = __attribute__((ext_vector_type(8))) short;  // 8 bf16 (4 VGPRs)
using f32x4  = __attribute__((ext_vector_type(4))) float;

static __device__ __forceinline__ unsigned short f2bf(float f) {
    unsigned int u = __float_as_uint(f);
    u += 0x7fff + ((u >> 16) & 1);       // round-to-nearest-even
    return (unsigned short)(u >> 16);
}
static __device__ __forceinline__ float bf2f(unsigned short u) {
    return __uint_as_float((unsigned)u << 16);
}

// ---------------- Kernel 1: x NCHW f32 -> channels-last bf16 [B][HW][64c] ----------------
__global__ __launch_bounds__(256)
void k_xpose(const float* __restrict__ x, unsigned short* __restrict__ xcl) {
    __shared__ unsigned short tile[64][66];   // 132B row stride (odd words) -> spread banks
    int b   = blockIdx.x / (HWp / 64);
    int px0 = (blockIdx.x % (HWp / 64)) * 64;
    int t = threadIdx.x;
    #pragma unroll
    for (int r = 0; r < 4; ++r) {                      // load: float4 per thread
        int c = r * 16 + (t >> 4), px4 = (t & 15) * 4;
        float4 v = *(const float4*)(x + ((size_t)b * Cc + c) * HWp + px0 + px4);
        tile[c][px4 + 0] = f2bf(v.x);
        tile[c][px4 + 1] = f2bf(v.y);
        tile[c][px4 + 2] = f2bf(v.z);
        tile[c][px4 + 3] = f2bf(v.w);
    }
    __syncthreads();
    #pragma unroll
    for (int r = 0; r < 4; ++r) {                      // store: ushort4 per thread
        int pxl = r * 16 + (t >> 4), c4 = (t & 15) * 4;
        ushort4 u;
        u.x = tile[c4 + 0][pxl];
        u.y = tile[c4 + 1][pxl];
        u.z = tile[c4 + 2][pxl];
        u.w = tile[c4 + 3][pxl];
        *(ushort4*)(xcl + ((size_t)b * HWp + px0 + pxl) * Cc + c4) = u;
    }
}

// ---------------- Kernel 2: pack W_def / W_cat / W_off into MFMA B-fragment order (bf16) ----------
// K-dim ordering for deform/offset GEMMs is kk-major: ck2 = kk*64 + c  (matches samp tile layout).
// B-frag (16x16x32): lane l, reg r holds B[k = ks*32 + (l>>4)*8 + r][n = ot*16 + (l&15)]
__global__ __launch_bounds__(256)
void k_wprep(const float* __restrict__ Wdef, const float* __restrict__ Wcat,
             const float* __restrict__ Woff,
             unsigned short* __restrict__ Fd, unsigned short* __restrict__ Fc,
             unsigned short* __restrict__ Fo) {
    int i = blockIdx.x * 256 + threadIdx.x;
    if (i < 4 * KSD * 64 * 8) {                       // Fd: [ot4][ks18][lane][r]
        int r = i & 7, lane = (i >> 3) & 63, ks = (i >> 9) % KSD, ot = (i >> 9) / KSD;
        int o  = ot * 16 + (lane & 15);
        int kp = ks * 32 + ((lane >> 4) << 3) + r;    // ck2 = kk*64 + c
        int kk = kp >> 6, c = kp & 63;
        Fd[i] = f2bf(Wdef[o * (Cc * KK) + c * KK + kk]);
    }
    int j = i - 4 * KSD * 64 * 8;
    if (j >= 0 && j < 4 * KSC * 64 * 8) {             // Fc: [ot4][ks2][lane][r]  (K = c, unchanged)
        int r = j & 7, lane = (j >> 3) & 63, ks = (j >> 9) & 1, ot = j >> 10;
        int o = ot * 16 + (lane & 15);
        int c = ks * 32 + ((lane >> 4) << 3) + r;
        Fc[j] = f2bf(Wcat[o * Cc + c]);
    }
    int m = j - 4 * KSC * 64 * 8;
    if (m >= 0 && m < 2 * KSD * 64 * 8) {             // Fo: [ot2][ks18][lane][r], oc>=18 zero-padded
        int r = m & 7, lane = (m >> 3) & 63, ks = (m >> 9) % KSD, ot = (m >> 9) / KSD;
        int o  = ot * 16 + (lane & 15);
        int kp = ks * 32 + ((lane >> 4) << 3) + r;
        int kk = kp >> 6, c = kp & 63;
        Fo[m] = (o < OFFC) ? f2bf(Woff[o * (Cc * KK) + c * KK + kk]) : 0;
    }
}

// ---------------- Kernel 3: FUSED offset-conv + deformable conv + 1x1 conv + BN partials --------
__global__ __launch_bounds__(256)
void k_fused(const unsigned short* __restrict__ xcl,
             const unsigned short* __restrict__ Fo, const float* __restrict__ boff,
             const unsigned short* __restrict__ Fd, const float* __restrict__ bdef,
             const unsigned short* __restrict__ Fc, const float* __restrict__ bcat,
             float* __restrict__ y, float* __restrict__ psum) {
    // s_buf: bf16 [32 px][576 ck2] swizzled (ck2 = kk*64+c); aliased fp32[64 o][32 px] in epilogue
    __shared__ __align__(16) unsigned char s_buf[PXB * Cc * KK * 2];   // 36864 B
    __shared__ __align__(16) unsigned char s_y1[PXB * Cc * 2];         // 4096 B
    __shared__ float s_off[PXB][OFFC];                                 // 2304 B
    __shared__ __align__(16) int s_pp[NIT * 8];                        // 9216 B: 4 idx + 4 wgt per item

    const int t = threadIdx.x;
    const int lane = t & 63, wv = t >> 6;
    const int klane = lane >> 4;
    const int c4 = (lane & 15) * 4;
    int wg = blockIdx.x;
    const int slot = wg & (SLOTS - 1);
    wg = (wg & 7) * (Bb * NBPX / 8) + (wg >> 3);   // XCD swizzle (4608 % 8 == 0 -> bijective)
    const int b   = wg / NBPX;
    const int px0 = (wg % NBPX) * PXB;
    const int h   = px0 / Ww;                      // uniform: PXB divides Ww
    const int w0  = px0 % Ww;
    const unsigned short* xb = xcl + (size_t)b * HWp * Cc;

    // ---- P0: plain 3x3 taps (zero-padded) -> s_buf; per item 16 lanes x ushort4
    #pragma unroll
    for (int it = 0; it < NIT / 16; ++it) {
        int item = it * 16 + wv * 4 + klane;       // 0..287
        int kk = item >> 5, pxl = item & 31;
        int ky = (kk * 11) >> 5, kx = kk - ky * 3;
        int row = h + ky - 1;
        int col = w0 + pxl + kx - 1;
        ushort4 u = {0, 0, 0, 0};
        if (row >= 0 && row < Hh && col >= 0 && col < Ww)
            u = *(const ushort4*)(xb + (size_t)(row * Ww + col) * Cc + c4);
        unsigned addr = (unsigned)pxl * (Cc * KK * 2)
                      + ((((unsigned)(kk * 64 + c4)) * 2) ^ ((unsigned)(pxl & 7) << 4));
        *(ushort4*)(s_buf + addr) = u;
    }
    __syncthreads();

    // ---- P0-MFMA: offsets[32px][18oc] = taps @ Woff^T ; waves: (oc-tile, px-tile)
    {
        const int pxt = wv & 1, oto = wv >> 1;
        const unsigned swzA = (unsigned)(lane & 7) << 4;
        const unsigned rA = ((unsigned)(lane & 15) + (unsigned)pxt * 16) * (Cc * KK * 2);
        f32x4 a = {0.f, 0.f, 0.f, 0.f};
        const bf16x8* Bo = (const bf16x8*)Fo + (size_t)oto * KSD * 64;
        #pragma unroll 3
        for (int ks = 0; ks < KSD; ++ks) {
            unsigned cb = ((unsigned)(ks * 64 + klane * 16)) ^ swzA;
            bf16x8 af = *(const bf16x8*)(s_buf + rA + cb);
            a = __builtin_amdgcn_mfma_f32_16x16x32_bf16(af, Bo[ks * 64 + lane], a, 0, 0, 0);
        }
        int oc = oto * 16 + (lane & 15);
        if (oc < OFFC) {
            float bv = boff[oc];
            #pragma unroll
            for (int r = 0; r < 4; ++r)
                s_off[pxt * 16 + klane * 4 + r][oc] = a[r] + bv;
        }
    }
    __syncthreads();

    // ---- P1a: bilinear params once per (tap,pixel) item -> s_pp
    for (int i = t; i < NIT; i += 256) {
        int kk = i >> 5, pxl = i & 31;
        int ky = (kk * 11) >> 5, kx = kk - ky * 3;
        float py  = s_off[pxl][kk * 2]     + (float)(h - 1 + ky);
        float pxf = s_off[pxl][kk * 2 + 1] + (float)(w0 + pxl - 1 + kx);
        float fy0 = floorf(py), fx0 = floorf(pxf);
        float wy = py - fy0, wx = pxf - fx0;
        int iy0 = (int)fy0, ix0 = (int)fx0, iy1 = iy0 + 1, ix1 = ix0 + 1;
        float v00 = (iy0 >= 0 && iy0 < Hh && ix0 >= 0 && ix0 < Ww) ? 1.f : 0.f;
        float v01 = (iy0 >= 0 && iy0 < Hh && ix1 >= 0 && ix1 < Ww) ? 1.f : 0.f;
        float v10 = (iy1 >= 0 && iy1 < Hh && ix0 >= 0 && ix0 < Ww) ? 1.f : 0.f;
        float v11 = (iy1 >= 0 && iy1 < Hh && ix1 >= 0 && ix1 < Ww) ? 1.f : 0.f;
        int cy0 = min(max(iy0, 0), Hh - 1), cy1 = min(max(iy1, 0), Hh - 1);
        int cx0 = min(max(ix0, 0), Ww - 1), cx1 = min(max(ix1, 0), Ww - 1);
        int* pp = &s_pp[i * 8];
        pp[0] = (cy0 * Ww + cx0) * (Cc * 2);       // byte offsets, pre-multiplied
        pp[1] = (cy0 * Ww + cx1) * (Cc * 2);
        pp[2] = (cy1 * Ww + cx0) * (Cc * 2);
        pp[3] = (cy1 * Ww + cx1) * (Cc * 2);
        pp[4] = __float_as_int((1.f - wy) * (1.f - wx) * v00);
        pp[5] = __float_as_int((1.f - wy) * wx * v01);
        pp[6] = __float_as_int(wy * (1.f - wx) * v10);
        pp[7] = __float_as_int(wy * wx * v11);
    }
    __syncthreads();

    // ---- P1b: vectorized bilinear gather -> s_buf overwrite (4 ch per lane)
    const unsigned char* xbB = (const unsigned char*)xb + (size_t)c4 * 2;
    #pragma unroll 2
    for (int it = 0; it < NIT / 16; ++it) {
        int item = it * 16 + wv * 4 + klane;
        int kk = item >> 5, pxl = item & 31;
        const int* pp = &s_pp[item * 8];
        int4   idx = *(const int4*)pp;             // broadcast within 16-lane group
        float4 wt  = *(const float4*)(pp + 4);
        ushort4 u00 = *(const ushort4*)(xbB + idx.x);
        ushort4 u01 = *(const ushort4*)(xbB + idx.y);
        ushort4 u10 = *(const ushort4*)(xbB + idx.z);
        ushort4 u11 = *(const ushort4*)(xbB + idx.w);
        float v0 = wt.x * bf2f(u00.x) + wt.y * bf2f(u01.x) + wt.z * bf2f(u10.x) + wt.w * bf2f(u11.x);
        float v1 = wt.x * bf2f(u00.y) + wt.y * bf2f(u01.y) + wt.z * bf2f(u10.y) + wt.w * bf2f(u11.y);
        float v2 = wt.x * bf2f(u00.z) + wt.y * bf2f(u01.z) + wt.z * bf2f(u10.z) + wt.w * bf2f(u11.z);
        float v3 = wt.x * bf2f(u00.w) + wt.y * bf2f(u01.w) + wt.z * bf2f(u10.w) + wt.w * bf2f(u11.w);
        ushort4 o4;
        o4.x = f2bf(v0); o4.y = f2bf(v1); o4.z = f2bf(v2); o4.w = f2bf(v3);
        unsigned addr = (unsigned)pxl * (Cc * KK * 2)
                      + ((((unsigned)(kk * 64 + c4)) * 2) ^ ((unsigned)(pxl & 7) << 4));
        *(ushort4*)(s_buf + addr) = o4;
    }
    __syncthreads();

    // ---- P2: deform GEMM  y1[32px][64o] = samp[32px][576] @ Wdef^T
    const int ot = wv;
    const unsigned swzA = (unsigned)(lane & 7) << 4;
    const unsigned rA0  = (unsigned)(lane & 15) * (Cc * KK * 2);
    const unsigned rA1  = rA0 + 16u * (Cc * KK * 2);
    f32x4 acc0 = {0.f, 0.f, 0.f, 0.f}, acc1 = {0.f, 0.f, 0.f, 0.f};
    const bf16x8* Bd = (const bf16x8*)Fd + (size_t)ot * KSD * 64;
    #pragma unroll 3
    for (int ks = 0; ks < KSD; ++ks) {
        unsigned cb = ((unsigned)(ks * 64 + klane * 16)) ^ swzA;
        bf16x8 a0 = *(const bf16x8*)(s_buf + rA0 + cb);
        bf16x8 a1 = *(const bf16x8*)(s_buf + rA1 + cb);
        bf16x8 bd = Bd[ks * 64 + lane];
        acc0 = __builtin_amdgcn_mfma_f32_16x16x32_bf16(a0, bd, acc0, 0, 0, 0);
        acc1 = __builtin_amdgcn_mfma_f32_16x16x32_bf16(a1, bd, acc1, 0, 0, 0);
    }
    const int o = ot * 16 + (lane & 15);
    {
        float bv = bdef[o];
        unsigned colb = (unsigned)o * 2;
        #pragma unroll
        for (int r = 0; r < 4; ++r) {
            int row0 = klane * 4 + r, row1 = row0 + 16;
            unsigned sw = (unsigned)(row0 & 7) << 4;
            *(unsigned short*)(s_y1 + row0 * (Cc * 2) + (colb ^ sw)) = f2bf(acc0[r] + bv);
            *(unsigned short*)(s_y1 + row1 * (Cc * 2) + (colb ^ sw)) = f2bf(acc1[r] + bv);
        }
    }
    __syncthreads();

    // ---- P3: 1x1 GEMM  yout[32px][64o] = y1 @ Wcat^T
    f32x4 c0 = {0.f, 0.f, 0.f, 0.f}, c1 = {0.f, 0.f, 0.f, 0.f};
    const bf16x8* Bc = (const bf16x8*)Fc + (size_t)ot * KSC * 64;
    const unsigned rY0 = (unsigned)(lane & 15) * (Cc * 2);
    const unsigned rY1 = rY0 + 16u * (Cc * 2);
    #pragma unroll
    for (int ks = 0; ks < KSC; ++ks) {
        unsigned cb = ((unsigned)(ks * 64 + klane * 16)) ^ swzA;
        bf16x8 a0 = *(const bf16x8*)(s_y1 + rY0 + cb);
        bf16x8 a1 = *(const bf16x8*)(s_y1 + rY1 + cb);
        bf16x8 bc = Bc[ks * 64 + lane];
        c0 = __builtin_amdgcn_mfma_f32_16x16x32_bf16(a0, bc, c0, 0, 0, 0);
        c1 = __builtin_amdgcn_mfma_f32_16x16x32_bf16(a1, bc, c1, 0, 0, 0);
    }

    // ---- BN partial stats from registers: per-channel sum / sumsq over this block's 32 px
    float vals[8];
    {
        float bcv = bcat[o];
        #pragma unroll
        for (int r = 0; r < 4; ++r) { vals[r] = c0[r] + bcv; vals[4 + r] = c1[r] + bcv; }
        float s1 = 0.f, s2 = 0.f;
        #pragma unroll
        for (int j = 0; j < 8; ++j) { s1 += vals[j]; s2 += vals[j] * vals[j]; }
        s1 += __shfl_xor(s1, 16); s1 += __shfl_xor(s1, 32);
        s2 += __shfl_xor(s2, 16); s2 += __shfl_xor(s2, 32);
        if (klane == 0) {
            atomicAdd(&psum[o * SLOTS + slot], s1);
            atomicAdd(&psum[Cc * SLOTS + o * SLOTS + slot], s2);
        }
    }

    // ---- Epilogue: transpose via LDS (aliases s_buf) -> coalesced float4 stores
    __syncthreads();     // all s_buf readers (P2) are past the s_y1 barrier; fence before overwrite
    {
        unsigned orow = (unsigned)o * (PXB * 4);
        unsigned sw   = (unsigned)(o & 7) << 4;
        #pragma unroll
        for (int r = 0; r < 4; ++r) {
            int p0 = klane * 4 + r, p1 = p0 + 16;
            *(float*)(s_buf + orow + (((unsigned)p0 * 4) ^ sw)) = vals[r];
            *(float*)(s_buf + orow + (((unsigned)p1 * 4) ^ sw)) = vals[4 + r];
        }
    }
    __syncthreads();
    float* yb = y + (size_t)b * Cc * HWp + px0;
    #pragma unroll
    for (int it = 0; it < 2; ++it) {
        int oo = it * 32 + (t >> 3), pxq = t & 7;
        float4 v = *(const float4*)(s_buf + (unsigned)oo * (PXB * 4)
                                    + (((unsigned)pxq * 16) ^ ((unsigned)(oo & 7) << 4)));
        *(float4*)(yb + (size_t)oo * HWp + pxq * 4) = v;
    }
}

// ---------------- Kernel 4: combine slotted partials -> mean/invstd ----------------
__global__ __launch_bounds__(64)
void k_stats_final(const float* __restrict__ psum, float* __restrict__ stats) {
    int c = threadIdx.x;              // 64 threads
    double t1 = 0.0, t2 = 0.0;
    for (int s = 0; s < SLOTS; ++s) {
        t1 += (double)psum[c * SLOTS + s];
        t2 += (double)psum[Cc * SLOTS + c * SLOTS + s];
    }
    double n = (double)(Bb * HWp);
    double mean = t1 / n;
    double var  = t2 / n - mean * mean;
    stats[c]      = (float)mean;
    stats[Cc + c] = (float)(1.0 / sqrt(var + 1e-5));
}

// ---------------- Kernel 5: BN apply + ReLU + residual (float4) ----------------
__global__ __launch_bounds__(256)
void k_apply(const float4* __restrict__ y, const float4* __restrict__ x,
             const float* __restrict__ stats, const float* __restrict__ gamma,
             const float* __restrict__ beta, float4* __restrict__ out) {
    int idx = blockIdx.x * 256 + threadIdx.x;           // over B*C*HW/4
    int c = (idx / (HWp / 4)) % Cc;
    float mean = stats[c], inv = stats[Cc + c];
    float g = gamma[c], bt = beta[c];
    float4 yv = y[idx], xv = x[idx], o;
    o.x = fmaxf(g * ((yv.x - mean) * inv) + bt, 0.f) + xv.x;
    o.y = fmaxf(g * ((yv.y - mean) * inv) + bt, 0.f) + xv.y;
    o.z = fmaxf(g * ((yv.z - mean) * inv) + bt, 0.f) + xv.z;
    o.w = fmaxf(g * ((yv.w - mean) * inv) + bt, 0.f) + xv.w;
    out[idx] = o;
}

extern "C" void kernel_launch(void* const* d_in, const int* in_sizes, int n_in,
                              void* d_out, int out_size, void* d_ws, size_t ws_size,
                              hipStream_t stream) {
    const float* x     = (const float*)d_in[0];
    const float* Woff  = (const float*)d_in[1];
    const float* boff  = (const float*)d_in[2];
    const float* Wdef  = (const float*)d_in[3];
    const float* bdef  = (const float*)d_in[4];
    const float* Wcat  = (const float*)d_in[5];
    const float* bcat  = (const float*)d_in[6];
    const float* gamma = (const float*)d_in[7];
    const float* beta  = (const float*)d_in[8];
    float* out = (float*)d_out;

    float* ws    = (float*)d_ws;
    float* ybuf  = ws;                                  // 9,437,184 f32
    float* stats = ybuf + (size_t)Bb * Cc * HWp;        // 128 f32
    float* psum  = stats + 128;                         // 2*64*SLOTS = 8192 f32
    unsigned short* Fd  = (unsigned short*)(psum + 2 * Cc * SLOTS);  // 36,864 u16 (16B-aligned)
    unsigned short* Fc  = Fd + 4 * KSD * 64 * 8;           // 4,096 u16
    unsigned short* Fo  = Fc + 4 * KSC * 64 * 8;           // 18,432 u16
    unsigned short* xcl = Fo + 2 * KSD * 64 * 8;           // 9,437,184 u16

    hipMemsetAsync(psum, 0, 2 * Cc * SLOTS * sizeof(float), stream);
    k_xpose<<<dim3(Bb * (HWp / 64)), dim3(256), 0, stream>>>(x, xcl);
    k_wprep<<<dim3((4 * KSD * 64 * 8 + 4 * KSC * 64 * 8 + 2 * KSD * 64 * 8 + 255) / 256),
              dim3(256), 0, stream>>>(Wdef, Wcat, Woff, Fd, Fc, Fo);
    k_fused<<<dim3(Bb * NBPX), dim3(256), 0, stream>>>(xcl, Fo, boff, Fd, bdef, Fc, bcat, ybuf, psum);
    k_stats_final<<<dim3(1), dim3(64), 0, stream>>>(psum, stats);
    k_apply<<<dim3(Bb * Cc * HWp / 4 / 256), dim3(256), 0, stream>>>(
        (const float4*)ybuf, (const float4*)x, stats, gamma, beta, (float4*)out);
}